// Round 1
// 1087.267 us; speedup vs baseline: 1.0246x; 1.0246x over previous
//
#include <hip/hip_runtime.h>

#define LN_EPS 1e-5f

// B=32768, F=64, D=128, all fp32.
// out[bt,i,d] = LN_d( x[bt,i]*W[i,d] + b[i,d] ) * gamma[d] + beta[d]
//
// Key algebraic identity: e[d] = x*W[d] + b[d] is AFFINE in x, so
//   mean   = x*E[W] + E[b]
//   var    = x^2*Var(W) + 2x*Cov(W,b) + Var(b)
// -> no per-iteration cross-lane reduction. The five per-feature moments are
// computed ONCE per wave via two butterfly rounds (25 shuffles, amortized over
// 128 iterations), replacing 10 shuffles *per iteration* in the old kernel.
// The loop body is then: 1 dword load (prefetched one iteration ahead),
// ~20 VALU, 1 float4 store -> pure streaming-write bound.
//
// Mapping (unchanged): each 32-lane half-wave owns one output row (128 floats,
// 4/lane as float4). Each wave pins one feature PAIR (i, i+1); its two
// half-rows are adjacent -> each wave store is 1 KiB fully contiguous.
// Grid-stride over batches. 2048 blocks x 256 thr = 8192 waves = 32 waves/CU.

__global__ __launch_bounds__(256) void tabemb_ln_kernel(
    const float* __restrict__ x,     // [32768, 64]
    const float* __restrict__ W,     // [64, 128]
    const float* __restrict__ b,     // [64, 128]
    const float* __restrict__ gamma, // [128]
    const float* __restrict__ beta,  // [128]
    float* __restrict__ out,         // [32768, 64, 128]
    int batch)
{
    const int gw   = (blockIdx.x << 2) + (threadIdx.x >> 6); // global wave 0..8191
    const int lane = threadIdx.x & 63;
    const int half = lane >> 5;             // which row of the pair
    const int l    = lane & 31;             // lane within row
    const int fp   = gw & 31;               // feature pair 0..31
    const int i    = (fp << 1) + half;      // feature index 0..63
    const int d0   = l << 2;                // embed start 0..124

    // Register-resident per-wave constants
    const float4 w4  = *(const float4*)(W     + (i << 7) + d0);
    const float4 b4  = *(const float4*)(b     + (i << 7) + d0);
    const float4 g4  = *(const float4*)(gamma + d0);
    const float4 be4 = *(const float4*)(beta  + d0);

    // ---- one-time per-feature moments (two half-wave butterflies) ----
    // Round 1: sums of W and b over the 128-wide row.
    float sw = (w4.x + w4.y) + (w4.z + w4.w);
    float sb = (b4.x + b4.y) + (b4.z + b4.w);
    #pragma unroll
    for (int m = 1; m <= 16; m <<= 1) {     // masks <32 never cross half-wave
        sw += __shfl_xor(sw, m, 64);
        sb += __shfl_xor(sb, m, 64);
    }
    const float mW = sw * 0.0078125f;       // E[W]
    const float mB = sb * 0.0078125f;       // E[b]

    // Round 2: centered second moments (numerically the two-pass variance).
    const float dw0 = w4.x - mW, dw1 = w4.y - mW, dw2 = w4.z - mW, dw3 = w4.w - mW;
    const float db0 = b4.x - mB, db1 = b4.y - mB, db2 = b4.z - mB, db3 = b4.w - mB;
    float sww = fmaf(dw0, dw0, fmaf(dw1, dw1, fmaf(dw2, dw2, dw3 * dw3)));
    float swb = fmaf(dw0, db0, fmaf(dw1, db1, fmaf(dw2, db2, dw3 * db3)));
    float sbb = fmaf(db0, db0, fmaf(db1, db1, fmaf(db2, db2, db3 * db3)));
    #pragma unroll
    for (int m = 1; m <= 16; m <<= 1) {
        sww += __shfl_xor(sww, m, 64);
        swb += __shfl_xor(swb, m, 64);
        sbb += __shfl_xor(sbb, m, 64);
    }
    const float vW   = sww * 0.0078125f;    // Var(W)
    const float cWB2 = swb * 0.015625f;     // 2*Cov(W,b)
    const float vB   = sbb * 0.0078125f;    // Var(b)

    const int    bstart  = gw >> 5;         // 0..255
    const int    bstride = 256;             // (8192 waves)/(32 pairs)
    const size_t rowoff  = ((size_t)i << 7) + (size_t)d0;

    // Software-pipelined x load: issue next iteration's load before computing.
    float xv = x[(bstart << 6) + i];        // same addr across half-wave -> HW broadcast
    for (int bt = bstart; bt < batch; bt += bstride) {
        const int btn = bt + bstride;
        float xn = 0.0f;
        if (btn < batch) xn = x[(btn << 6) + i];

        const float mean = fmaf(xv, mW, mB);
        const float var  = fmaf(xv, fmaf(xv, vW, cWB2), vB);  // x^2 vW + 2x cov + vB
        const float inv  = rsqrtf(var + LN_EPS);

        float4 o; float e, c1, c0;
        e = fmaf(xv, w4.x, b4.x); c1 = inv * g4.x; c0 = fmaf(-mean, c1, be4.x); o.x = fmaf(e, c1, c0);
        e = fmaf(xv, w4.y, b4.y); c1 = inv * g4.y; c0 = fmaf(-mean, c1, be4.y); o.y = fmaf(e, c1, c0);
        e = fmaf(xv, w4.z, b4.z); c1 = inv * g4.z; c0 = fmaf(-mean, c1, be4.z); o.z = fmaf(e, c1, c0);
        e = fmaf(xv, w4.w, b4.w); c1 = inv * g4.w; c0 = fmaf(-mean, c1, be4.w); o.w = fmaf(e, c1, c0);

        *(float4*)(out + (size_t)bt * 8192 + rowoff) = o;
        xv = xn;
    }
}

extern "C" void kernel_launch(void* const* d_in, const int* in_sizes, int n_in,
                              void* d_out, int out_size, void* d_ws, size_t ws_size,
                              hipStream_t stream) {
    const float* x     = (const float*)d_in[0];
    const float* W     = (const float*)d_in[1];
    const float* b     = (const float*)d_in[2];
    const float* gamma = (const float*)d_in[3];
    const float* beta  = (const float*)d_in[4];
    float* out = (float*)d_out;

    const int batch = in_sizes[0] / 64;  // 32768

    tabemb_ln_kernel<<<2048, 256, 0, stream>>>(x, W, b, gamma, beta, out, batch);
}